// Round 4
// baseline (200.819 us; speedup 1.0000x reference)
//
#include <hip/hip_runtime.h>
#include <hip/hip_cooperative_groups.h>
#include <math.h>

namespace cg = cooperative_groups;

// Problem constants (fixed by reference setup_inputs)
#define BB 128
#define LL 512
#define DD 256
#define TT 64
#define GG 8     // LL / TT
#define NQ (DD/4)  // 64 f32x4 per D-row

typedef float f32x4 __attribute__((ext_vector_type(4)));

__device__ __forceinline__ float sigm(float x) {
    return 1.0f / (1.0f + __expf(-x));
}
__device__ __forceinline__ f32x4 sigm4(f32x4 z) {
    f32x4 r;
    r.x = sigm(z.x); r.y = sigm(z.y); r.z = sigm(z.z); r.w = sigm(z.w);
    return r;
}

// ============================ Cooperative path ============================
// 1024 blocks x 256 threads, 4 blocks/CU (VGPR<=128, LDS 36.9KB/block).
// Block (b,t8) owns 64 rows (8 t-groups); wave w owns 16 rows (t-groups
// t8*8+2w, +1). Even t-group rows of aco held in 8 f32x4 registers, odd
// t-group rows in LDS. vis is streamed (pooled only) and re-read in phase C
// (L3-resident). Outputs NT-stored.
__global__ __launch_bounds__(256, 4) void k_fused(
    const f32x4* __restrict__ aco4, const f32x4* __restrict__ vis4,
    const int* __restrict__ isb,
    const float* __restrict__ Wh, const float* __restrict__ bh,
    const float* __restrict__ Ww, const float* __restrict__ bw,
    const float* __restrict__ cw, const float* __restrict__ cb,
    f32x4* __restrict__ out4,
    float* __restrict__ rowMean,   // [BB*TT]
    float* __restrict__ colpart)   // [1024*DD]
{
    cg::grid_group grid = cg::this_grid();

    __shared__ f32x4 acoL[4 * 8 * 64];             // 32 KB: odd t-group rows
    __shared__ __align__(16) float red[4 * DD];    // 4 KB: cpart, reused for gates

    const int tid  = threadIdx.x;
    const int w    = tid >> 6;
    const int lane = tid & 63;
    const int bk   = blockIdx.x;
    const int b    = bk >> 3;
    const int t8   = bk & 7;

    const size_t rowBase = (size_t)b * LL + (size_t)t8 * 64 + (size_t)w * 16;
    const size_t N4 = (size_t)BB * LL * NQ;

    // ---- Phase A: read inputs once, pool, stash aco on-chip ----
    f32x4 A[8];
    f32x4 pa0 = 0.f;
#pragma unroll
    for (int j = 0; j < 8; ++j) {
        A[j] = aco4[(rowBase + j) * NQ + lane];
        pa0 += A[j];
    }
    f32x4 pa1 = 0.f;
#pragma unroll
    for (int j = 0; j < 8; ++j) {
        f32x4 v = aco4[(rowBase + 8 + j) * NQ + lane];
        acoL[(w * 8 + j) * 64 + lane] = v;
        pa1 += v;
    }
    f32x4 pv0 = 0.f, pv1 = 0.f;
#pragma unroll
    for (int j = 0; j < 8; ++j) pv0 += vis4[(rowBase + j) * NQ + lane];
#pragma unroll
    for (int j = 0; j < 8; ++j) pv1 += vis4[(rowBase + 8 + j) * NQ + lane];

    pa0 *= 0.125f; pa1 *= 0.125f; pv0 *= 0.125f; pv1 *= 0.125f;

    const float cw0 = cw[0], cw1 = cw[1], cb0 = cb[0];
    const f32x4 c0 = sigm4(cw0 * pa0 + cw1 * pv0 + cb0);
    const f32x4 c1 = sigm4(cw0 * pa1 + cw1 * pv1 + cb0);
    const f32x4 hw0 = 0.5f * (pa0 + pv0);
    const f32x4 hw1 = 0.5f * (pa1 + pv1);

    // row means over D for the wave's two t-groups
    float s0 = hw0.x + hw0.y + hw0.z + hw0.w;
    float s1 = hw1.x + hw1.y + hw1.z + hw1.w;
#pragma unroll
    for (int off = 32; off > 0; off >>= 1) {
        s0 += __shfl_xor(s0, off, 64);
        s1 += __shfl_xor(s1, off, 64);
    }
    if (lane == 0) {
        const int btBase = b * TT + t8 * 8 + 2 * w;
        rowMean[btBase]     = s0 * (1.0f / DD);
        rowMean[btBase + 1] = s1 * (1.0f / DD);
    }

    // column partial (sum of hw over this block's 8 t-groups, per d)
    *reinterpret_cast<f32x4*>(&red[w * DD + lane * 4]) = hw0 + hw1;
    __syncthreads();
    colpart[(size_t)bk * DD + tid] =
        red[tid] + red[DD + tid] + red[2 * DD + tid] + red[3 * DD + tid];

    grid.sync();

    // ---- Phase C: gates from summaries (red[] reused) ----
    float* cm = red;               // [256]
    float* wv = red + DD;          // [256]
    float* rm = red + 2 * DD;      // [64]
    float* hv = red + 2 * DD + TT; // [8]

    {
        float cs = 0.f;
#pragma unroll
        for (int p = 0; p < 8; ++p)
            cs += colpart[(size_t)(b * 8 + p) * DD + tid];
        cm[tid] = cs * (1.0f / TT);
        if (tid < TT) rm[tid] = rowMean[b * TT + tid];
    }
    __syncthreads();

    if (tid < 8) {
        const int t = t8 * 8 + tid;
        float acc = bh[t];
#pragma unroll 8
        for (int j = 0; j < TT; ++j) acc += rm[j] * Wh[t * TT + j];
        hv[tid] = sigm(acc);
    }
    {
        float acc = bw[tid];
        const f32x4* Wr = reinterpret_cast<const f32x4*>(Ww + (size_t)tid * DD);
#pragma unroll 8
        for (int kq = 0; kq < NQ; ++kq) {
            f32x4 wq = Wr[kq];
            acc += cm[4 * kq] * wq.x + cm[4 * kq + 1] * wq.y +
                   cm[4 * kq + 2] * wq.z + cm[4 * kq + 3] * wq.w;
        }
        wv[tid] = sigm(acc);
    }
    __syncthreads();

    // ---- Apply: aco from on-chip copy, vis re-read (L3), NT stores ----
    const float hA = hv[2 * w];
    const float hB = hv[2 * w + 1];
    f32x4 w4;
    w4.x = wv[lane * 4]; w4.y = wv[lane * 4 + 1];
    w4.z = wv[lane * 4 + 2]; w4.w = wv[lane * 4 + 3];
    const f32x4 scA = (hA + w4 + c0) * (1.0f / 3.0f);
    const f32x4 scB = (hB + w4 + c1) * (1.0f / 3.0f);

#pragma unroll
    for (int j = 0; j < 8; ++j) {
        const size_t ridx = rowBase + j;
        const size_t idx  = ridx * NQ + lane;
        const int m = isb[ridx];                    // wave-uniform
        f32x4 a = A[j];
        f32x4 v = vis4[idx];
        if (m == 1) { a *= scA; v *= scA; }
        __builtin_nontemporal_store(a, &out4[idx]);
        __builtin_nontemporal_store(v, &out4[N4 + idx]);
    }
#pragma unroll
    for (int j = 0; j < 8; ++j) {
        const size_t ridx = rowBase + 8 + j;
        const size_t idx  = ridx * NQ + lane;
        const int m = isb[ridx];
        f32x4 a = acoL[(w * 8 + j) * 64 + lane];
        f32x4 v = vis4[idx];
        if (m == 1) { a *= scB; v *= scB; }
        __builtin_nontemporal_store(a, &out4[idx]);
        __builtin_nontemporal_store(v, &out4[N4 + idx]);
    }
}

// ============================ Fallback path (proven R2) ============================
__global__ void k_pool(const f32x4* __restrict__ aco, const f32x4* __restrict__ vis,
                       const float* __restrict__ conv_w, const float* __restrict__ conv_b,
                       f32x4* __restrict__ c_att, f32x4* __restrict__ hw_buf,
                       float* __restrict__ hwRowMean)
{
    const int tid = threadIdx.x;
    const int q   = tid & 63;
    const int r   = tid >> 6;
    const int bt  = blockIdx.x * 4 + r;
    const int b   = bt >> 6;
    const int t   = bt & 63;

    size_t base = ((size_t)(b * LL + t * GG)) * NQ + q;
    f32x4 sa = 0.f, sv = 0.f;
#pragma unroll
    for (int g = 0; g < GG; ++g) {
        sa += aco[base + (size_t)g * NQ];
        sv += vis[base + (size_t)g * NQ];
    }
    sa *= 0.125f;
    sv *= 0.125f;

    const float cw0 = conv_w[0], cw1 = conv_w[1], cb = conv_b[0];
    f32x4 ca = sigm4(cw0 * sa + cw1 * sv + cb);
    f32x4 hw = 0.5f * (sa + sv);

    c_att[(size_t)bt * NQ + q]  = ca;
    hw_buf[(size_t)bt * NQ + q] = hw;

    float hsum = hw.x + hw.y + hw.z + hw.w;
#pragma unroll
    for (int off = 32; off > 0; off >>= 1)
        hsum += __shfl_xor(hsum, off, 64);
    if (q == 0) hwRowMean[bt] = hsum * (1.0f / DD);
}

__global__ void k_gates(const float* __restrict__ hw_buf, const float* __restrict__ hwRowMean,
                        const float* __restrict__ Wh, const float* __restrict__ bh,
                        const float* __restrict__ Ww, const float* __restrict__ bw,
                        float* __restrict__ h_att, float* __restrict__ w_att)
{
    const int b = blockIdx.x;
    const int d = threadIdx.x;

    __shared__ float row[TT];
    __shared__ float cm[DD];

    if (d < TT) row[d] = hwRowMean[b * TT + d];

    float s = 0.f;
    const float* hb = hw_buf + (size_t)b * TT * DD + d;
#pragma unroll
    for (int t = 0; t < TT; ++t) s += hb[(size_t)t * DD];
    cm[d] = s * (1.0f / TT);
    __syncthreads();

    if (d < TT) {
        float acc = bh[d];
#pragma unroll
        for (int j = 0; j < TT; ++j) acc += row[j] * Wh[d * TT + j];
        h_att[b * TT + d] = sigm(acc);
    }

    float acc = bw[d];
    const float* wr = Ww + (size_t)d * DD;
#pragma unroll 4
    for (int k = 0; k < DD; k += 4) {
        f32x4 w4 = *reinterpret_cast<const f32x4*>(wr + k);
        acc += cm[k] * w4.x + cm[k + 1] * w4.y + cm[k + 2] * w4.z + cm[k + 3] * w4.w;
    }
    w_att[b * DD + d] = sigm(acc);
}

__global__ void k_apply(const f32x4* __restrict__ aco, const f32x4* __restrict__ vis,
                        const int* __restrict__ isbag,
                        const f32x4* __restrict__ c_att, const float* __restrict__ h_att,
                        const f32x4* __restrict__ w_att,
                        f32x4* __restrict__ out)
{
    const size_t N4 = (size_t)BB * LL * NQ;
    const size_t stride = (size_t)gridDim.x * blockDim.x;
    for (size_t i = (size_t)blockIdx.x * blockDim.x + threadIdx.x; i < N4; i += stride) {
        const int row = (int)(i >> 6);
        const int dq  = (int)(i & 63);
        const int b   = row >> 9;
        const int l   = row & 511;
        const int t   = l >> 3;

        const float h  = h_att[b * TT + t];
        const f32x4 w4 = w_att[b * NQ + dq];
        const f32x4 c4 = c_att[((size_t)(b * TT + t)) * NQ + dq];
        const bool  m  = (isbag[row] == 1);

        f32x4 a4 = aco[i];
        f32x4 v4 = vis[i];
        f32x4 s4 = (h + w4 + c4) * (1.0f / 3.0f);

        f32x4 oa = m ? (f32x4)(a4 * s4) : a4;
        f32x4 ov = m ? (f32x4)(v4 * s4) : v4;

        __builtin_nontemporal_store(oa, &out[i]);
        __builtin_nontemporal_store(ov, &out[N4 + i]);
    }
}

extern "C" void kernel_launch(void* const* d_in, const int* in_sizes, int n_in,
                              void* d_out, int out_size, void* d_ws, size_t ws_size,
                              hipStream_t stream) {
    const f32x4* aco = (const f32x4*)d_in[0];
    const f32x4* vis = (const f32x4*)d_in[1];
    const int*   isb = (const int*)d_in[2];
    const float* Wh  = (const float*)d_in[3];
    const float* bh  = (const float*)d_in[4];
    const float* Ww  = (const float*)d_in[5];
    const float* bw  = (const float*)d_in[6];
    const float* cw  = (const float*)d_in[7];
    const float* cb  = (const float*)d_in[8];
    f32x4* out = (f32x4*)d_out;

    float* ws = (float*)d_ws;
    // Cooperative-path buffers
    float* rowMean = ws;                          // BB*TT = 8192
    float* colpart = ws + BB * TT;                // 1024*DD = 262144
    // Fallback buffers (disjoint region)
    float* fb        = ws + BB * TT + 1024 * DD;
    float* c_att     = fb;                               // BB*TT*DD
    float* hw_buf    = c_att  + (size_t)BB * TT * DD;    // BB*TT*DD
    float* hwRowMean = hw_buf + (size_t)BB * TT * DD;    // BB*TT
    float* h_att     = hwRowMean + BB * TT;              // BB*TT
    float* w_att     = h_att + BB * TT;                  // BB*DD

    void* kp[] = {
        (void*)&aco, (void*)&vis, (void*)&isb,
        (void*)&Wh, (void*)&bh, (void*)&Ww, (void*)&bw,
        (void*)&cw, (void*)&cb, (void*)&out,
        (void*)&rowMean, (void*)&colpart
    };
    hipError_t rc = hipLaunchCooperativeKernel((const void*)k_fused,
                                               dim3(1024), dim3(256),
                                               kp, 0, stream);
    if (rc != hipSuccess) {
        (void)hipGetLastError();  // clear error state
        k_pool<<<BB * TT / 4, 256, 0, stream>>>(aco, vis, cw, cb,
                                                (f32x4*)c_att, (f32x4*)hw_buf, hwRowMean);
        k_gates<<<BB, DD, 0, stream>>>(hw_buf, hwRowMean, Wh, bh, Ww, bw, h_att, w_att);
        k_apply<<<2048, 256, 0, stream>>>(aco, vis, isb,
                                          (const f32x4*)c_att, h_att, (const f32x4*)w_att,
                                          out);
    }
}

// Round 5
// 75.414 us; speedup vs baseline: 2.6629x; 2.6629x over previous
//
#include <hip/hip_runtime.h>
#include <math.h>

// Problem constants (fixed by reference setup_inputs)
#define BB 128
#define LL 512
#define DD 256
#define TT 64
#define GG 8       // LL / TT
#define NQ (DD/4)  // 64 f32x4 per D-row

typedef float f32x4 __attribute__((ext_vector_type(4)));

__device__ __forceinline__ float sigm(float x) {
    return 1.0f / (1.0f + __expf(-x));
}
__device__ __forceinline__ f32x4 sigm4(f32x4 z) {
    f32x4 r;
    r.x = sigm(z.x); r.y = sigm(z.y); r.z = sigm(z.z); r.w = sigm(z.w);
    return r;
}

// ---------------- K1: summaries only ----------------
// grid = 1024 blocks (b, t8-chunk) x 256 threads. Wave w owns t-groups
// (t8*8 + 2w, +1), i.e. 16 rows. Emits rowMean[b,t] (hw mean over D) and
// colpart[bk,d] (hw summed over this block's 8 t-groups). No bulk writes.
__global__ __launch_bounds__(256) void k_sum(
    const f32x4* __restrict__ aco4, const f32x4* __restrict__ vis4,
    float* __restrict__ rowMean,   // [BB*TT]
    float* __restrict__ colpart)   // [1024*DD]
{
    const int tid  = threadIdx.x;
    const int w    = tid >> 6;
    const int lane = tid & 63;
    const int bk   = blockIdx.x;
    const int b    = bk >> 3;
    const int t8   = bk & 7;

    const size_t rowBase = (size_t)b * LL + (size_t)t8 * 64 + (size_t)w * 16;

    // hw = 0.5*(mean_a + mean_v) = (sum over 8 rows of (a+v)) / 16
    f32x4 hw0 = 0.f, hw1 = 0.f;
#pragma unroll
    for (int j = 0; j < 8; ++j)
        hw0 += aco4[(rowBase + j) * NQ + lane] + vis4[(rowBase + j) * NQ + lane];
#pragma unroll
    for (int j = 0; j < 8; ++j)
        hw1 += aco4[(rowBase + 8 + j) * NQ + lane] + vis4[(rowBase + 8 + j) * NQ + lane];
    hw0 *= 0.0625f;
    hw1 *= 0.0625f;

    // row means over D for the wave's two t-groups (64 lanes = 1 wave)
    float s0 = hw0.x + hw0.y + hw0.z + hw0.w;
    float s1 = hw1.x + hw1.y + hw1.z + hw1.w;
#pragma unroll
    for (int off = 32; off > 0; off >>= 1) {
        s0 += __shfl_xor(s0, off, 64);
        s1 += __shfl_xor(s1, off, 64);
    }
    if (lane == 0) {
        const int btBase = b * TT + t8 * 8 + 2 * w;
        rowMean[btBase]     = s0 * (1.0f / DD);
        rowMean[btBase + 1] = s1 * (1.0f / DD);
    }

    // per-block column partial (sum of hw over 8 t-groups, per d)
    __shared__ __align__(16) float red[4][DD];
    *reinterpret_cast<f32x4*>(&red[w][lane * 4]) = hw0 + hw1;
    __syncthreads();
    colpart[(size_t)bk * DD + tid] =
        red[0][tid] + red[1][tid] + red[2][tid] + red[3][tid];
}

// ---------------- K2: gates ----------------
// grid = BB x 256 threads. h_att = sigm(rowMean @ Wh^T + bh),
// w_att = sigm(colMean @ Ww^T + bw).
__global__ __launch_bounds__(256) void k_gates(
    const float* __restrict__ colpart, const float* __restrict__ rowMean,
    const float* __restrict__ Wh, const float* __restrict__ bh,
    const float* __restrict__ Ww, const float* __restrict__ bw,
    float* __restrict__ h_att, float* __restrict__ w_att)
{
    const int b = blockIdx.x;
    const int d = threadIdx.x;

    __shared__ float rm[TT];
    __shared__ float cm[DD];

    {
        float cs = 0.f;
#pragma unroll
        for (int p = 0; p < 8; ++p)
            cs += colpart[(size_t)(b * 8 + p) * DD + d];
        cm[d] = cs * (1.0f / TT);
        if (d < TT) rm[d] = rowMean[b * TT + d];
    }
    __syncthreads();

    if (d < TT) {
        float acc = bh[d];
#pragma unroll 8
        for (int j = 0; j < TT; ++j) acc += rm[j] * Wh[d * TT + j];
        h_att[b * TT + d] = sigm(acc);
    }
    {
        float acc = bw[d];
        const f32x4* Wr = reinterpret_cast<const f32x4*>(Ww + (size_t)d * DD);
#pragma unroll 8
        for (int kq = 0; kq < NQ; ++kq) {
            f32x4 wq = Wr[kq];
            acc += cm[4 * kq] * wq.x + cm[4 * kq + 1] * wq.y +
                   cm[4 * kq + 2] * wq.z + cm[4 * kq + 3] * wq.w;
        }
        w_att[b * DD + d] = sigm(acc);
    }
}

// ---------------- K3: pool-recompute + apply ----------------
// grid = 8192 blocks (b, t) x 256 threads (r=tid>>6 in 0..3, q=tid&63).
// Thread owns rows (t*8 + r) and (t*8 + r + 4), one f32x4 column each.
// Pools its own 8-row group in LDS (bytes already needed for apply),
// recomputes c_att locally, applies scale, NT-stores both outputs.
__global__ __launch_bounds__(256) void k_apply(
    const f32x4* __restrict__ aco4, const f32x4* __restrict__ vis4,
    const int* __restrict__ isb,
    const float* __restrict__ h_att, const float* __restrict__ w_att,
    const float* __restrict__ cw, const float* __restrict__ cb,
    f32x4* __restrict__ out4)
{
    const int tid = threadIdx.x;
    const int r   = tid >> 6;
    const int q   = tid & 63;
    const int bk  = blockIdx.x;
    const int b   = bk >> 6;
    const int t   = bk & 63;

    const size_t row0 = (size_t)b * LL + (size_t)t * GG + r;  // rows r, r+4
    const size_t N4   = (size_t)BB * LL * NQ;

    const size_t i0 = row0 * NQ + q;
    const size_t i1 = (row0 + 4) * NQ + q;

    f32x4 a0 = aco4[i0], a1 = aco4[i1];
    f32x4 v0 = vis4[i0], v1 = vis4[i1];

    __shared__ __align__(16) f32x4 redA[4][64];
    __shared__ __align__(16) f32x4 redV[4][64];
    redA[r][q] = a0 + a1;
    redV[r][q] = v0 + v1;
    __syncthreads();

    const f32x4 pa = (redA[0][q] + redA[1][q] + redA[2][q] + redA[3][q]) * 0.125f;
    const f32x4 pv = (redV[0][q] + redV[1][q] + redV[2][q] + redV[3][q]) * 0.125f;

    const f32x4 c  = sigm4(cw[0] * pa + cw[1] * pv + cb[0]);
    const float h  = h_att[b * TT + t];
    const f32x4 w4 = *reinterpret_cast<const f32x4*>(w_att + (size_t)b * DD + q * 4);
    const f32x4 sc = (h + w4 + c) * (1.0f / 3.0f);

    const int m0 = isb[row0];
    const int m1 = isb[row0 + 4];
    if (m0 == 1) { a0 *= sc; v0 *= sc; }
    if (m1 == 1) { a1 *= sc; v1 *= sc; }

    __builtin_nontemporal_store(a0, &out4[i0]);
    __builtin_nontemporal_store(a1, &out4[i1]);
    __builtin_nontemporal_store(v0, &out4[N4 + i0]);
    __builtin_nontemporal_store(v1, &out4[N4 + i1]);
}

extern "C" void kernel_launch(void* const* d_in, const int* in_sizes, int n_in,
                              void* d_out, int out_size, void* d_ws, size_t ws_size,
                              hipStream_t stream) {
    const f32x4* aco = (const f32x4*)d_in[0];
    const f32x4* vis = (const f32x4*)d_in[1];
    const int*   isb = (const int*)d_in[2];
    const float* Wh  = (const float*)d_in[3];
    const float* bh  = (const float*)d_in[4];
    const float* Ww  = (const float*)d_in[5];
    const float* bw  = (const float*)d_in[6];
    const float* cw  = (const float*)d_in[7];
    const float* cb  = (const float*)d_in[8];
    f32x4* out = (f32x4*)d_out;

    float* ws = (float*)d_ws;
    float* rowMean = ws;                          // BB*TT      = 8192 floats
    float* colpart = rowMean + BB * TT;           // 1024*DD    = 262144 floats
    float* h_att   = colpart + 1024 * DD;         // BB*TT      = 8192 floats
    float* w_att   = h_att + BB * TT;             // BB*DD      = 32768 floats

    k_sum<<<1024, 256, 0, stream>>>(aco, vis, rowMean, colpart);
    k_gates<<<BB, 256, 0, stream>>>(colpart, rowMean, Wh, bh, Ww, bw, h_att, w_att);
    k_apply<<<BB * TT, 256, 0, stream>>>(aco, vis, isb, h_att, w_att, cw, cb, out);
}